// Round 5
// baseline (238.070 us; speedup 1.0000x reference)
//
#include <hip/hip_runtime.h>

typedef __attribute__((ext_vector_type(8))) __bf16 bf16x8;
typedef __attribute__((ext_vector_type(4))) float f32x4;
typedef __attribute__((ext_vector_type(16))) float f32x16;
typedef unsigned short u16;

#define MFMA16(a, b, c) __builtin_amdgcn_mfma_f32_16x16x32_bf16(a, b, c, 0, 0, 0)
#define MFMA32(a, b, c) __builtin_amdgcn_mfma_f32_32x32x16_bf16(a, b, c, 0, 0, 0)

// HW packed fp32->bf16 (RNE), 2 values per instruction. No builtin on gfx950.
__device__ __forceinline__ unsigned cvt2(float a, float b) {
    unsigned r;
    asm("v_cvt_pk_bf16_f32 %0, %1, %2" : "=v"(r) : "v"(a), "v"(b));
    return r;  // lo16 = bf16(a), hi16 = bf16(b)
}
__device__ __forceinline__ u16 cvt1(float a) { return (u16)cvt2(a, a); }
__device__ __forceinline__ float lo2f(unsigned p) { return __uint_as_float(p << 16); }
__device__ __forceinline__ float hi2f(unsigned p) { return __uint_as_float(p & 0xffff0000u); }

// 16x16 LDS fragment (stride 72 u16): row = rtile+(lane&15), k = kofs+(lane>>4)*8
__device__ __forceinline__ bf16x8 frag(const u16* base, int rtile, int lane, int kofs) {
    return *(const bf16x8*)(base + (rtile + (lane & 15)) * 72 + kofs + (lane >> 4) * 8);
}
// 32x32 LDS fragment, swizzled [rows][64] layout: k-granule XOR'd by (row&7)
__device__ __forceinline__ bf16x8 frag32(const u16* base, int rtile, int lane, int kofs) {
    int row = rtile + (lane & 31);
    int ks  = kofs + (lane >> 5) * 8;
    return *(const bf16x8*)(base + row * 64 + (ks ^ ((row & 7) << 3)));
}

// ---------------------------------------------------------------------------
// Fused partial: for k-quarter kq (blockIdx.y), 128 rows (blockIdx.x):
//   Qp[kq] = x*Wq^T, Kp[kq] = x*Wk^T (fp32 partials)
//   fcp[kq] = x*W1^T (fp32, 3-product bf16 split)
// 256 threads / 4 waves, 32x32x16 MFMA. Wave = (rh: 64 rows, ch: 32 cols).
// 40 FLOP per LDS-read-byte (vs 16 for the 16x16 design). LDS 64KB, 2 blk/CU.
// ---------------------------------------------------------------------------
__global__ __launch_bounds__(256, 2) void qkf_kernel(
    const float* __restrict__ x, const float* __restrict__ Wq,
    const float* __restrict__ Wk, const float* __restrict__ W1,
    float* __restrict__ Qp, float* __restrict__ Kp, float* __restrict__ fcp)
{
    __shared__ __align__(16) u16 SM[32768];
    u16* Xh  = SM;             // [128][64] swizzled
    u16* Xl  = SM + 8192;
    u16* Wqh = SM + 16384;     // [64][64] swizzled
    u16* Wkh = SM + 20480;
    u16* W1h = SM + 24576;
    u16* W1l = SM + 28672;

    const int tid  = threadIdx.x;
    const int lane = tid & 63;
    const int wv   = tid >> 6;        // 0..3
    const int rh   = wv >> 1;         // row half: rows rh*64 .. +63
    const int ch   = wv & 1;          // col tile: cols ch*32 .. +31
    const long row0 = (long)blockIdx.x * 128;
    const int kb   = blockIdx.y * 256;           // k-quarter base
    const long sOf = (long)blockIdx.y * 1048576; // output slab offset

    f32x16 qa0 = {}, qa1 = {}, ka0 = {}, ka1 = {}, fa0 = {}, fa1 = {};

    // staging coords
    const int sxr = tid >> 1;          // x row 0..127
    const int sxk = (tid & 1) * 32;    // x k base
    const int xsw = (sxr & 7) << 3;
    const int swr = tid >> 2;          // weight row 0..63
    const int swk = (tid & 3) * 16;    // weight k base
    const int wsw = (swr & 7) << 3;

    float4 xv[8], qv[4], kv[4], w1v[4];

#define LOAD_X(K0)                                                            \
    { _Pragma("unroll")                                                       \
      for (int i = 0; i < 8; ++i)                                             \
          xv[i] = *(const float4*)(x + (row0 + sxr) * 1024 + (K0) + sxk + i * 4); }
#define LOAD_W(K0)                                                            \
    { _Pragma("unroll")                                                       \
      for (int i = 0; i < 4; ++i) {                                           \
          qv[i]  = *(const float4*)(Wq + (long)swr * 1024 + (K0) + swk + i * 4); \
          kv[i]  = *(const float4*)(Wk + (long)swr * 1024 + (K0) + swk + i * 4); \
          w1v[i] = *(const float4*)(W1 + (long)swr * 1024 + (K0) + swk + i * 4); \
      } }
#define STAGE_X                                                               \
    { _Pragma("unroll")                                                       \
      for (int i = 0; i < 8; ++i) {                                           \
          int o = sxr * 64 + ((sxk + i * 4) ^ xsw);                           \
          unsigned h01 = cvt2(xv[i].x, xv[i].y);                              \
          unsigned h23 = cvt2(xv[i].z, xv[i].w);                              \
          unsigned l01 = cvt2(xv[i].x - lo2f(h01), xv[i].y - hi2f(h01));      \
          unsigned l23 = cvt2(xv[i].z - lo2f(h23), xv[i].w - hi2f(h23));      \
          uint2 t; t.x = h01; t.y = h23; *(uint2*)&Xh[o] = t;                 \
          t.x = l01; t.y = l23; *(uint2*)&Xl[o] = t;                          \
      } }
#define STAGE_W                                                               \
    { _Pragma("unroll")                                                       \
      for (int i = 0; i < 4; ++i) {                                           \
          int o = swr * 64 + ((swk + i * 4) ^ wsw);                           \
          uint2 t;                                                            \
          t.x = cvt2(qv[i].x, qv[i].y); t.y = cvt2(qv[i].z, qv[i].w);         \
          *(uint2*)&Wqh[o] = t;                                               \
          t.x = cvt2(kv[i].x, kv[i].y); t.y = cvt2(kv[i].z, kv[i].w);         \
          *(uint2*)&Wkh[o] = t;                                               \
          unsigned h01 = cvt2(w1v[i].x, w1v[i].y);                            \
          unsigned h23 = cvt2(w1v[i].z, w1v[i].w);                            \
          t.x = h01; t.y = h23; *(uint2*)&W1h[o] = t;                         \
          t.x = cvt2(w1v[i].x - lo2f(h01), w1v[i].y - hi2f(h01));             \
          t.y = cvt2(w1v[i].z - lo2f(h23), w1v[i].w - hi2f(h23));             \
          *(uint2*)&W1l[o] = t;                                               \
      } }

    LOAD_X(kb) LOAD_W(kb)
    for (int c = 0; c < 4; ++c) {
        if (c) __syncthreads();
        STAGE_X
        STAGE_W
        __syncthreads();
        if (c < 3) { LOAD_X(kb + (c + 1) * 64) LOAD_W(kb + (c + 1) * 64) }
#pragma unroll
        for (int s = 0; s < 4; ++s) {
            const int ko = s * 16;
            bf16x8 xh0 = frag32(Xh, rh * 64,      lane, ko);
            bf16x8 xh1 = frag32(Xh, rh * 64 + 32, lane, ko);
            bf16x8 xl0 = frag32(Xl, rh * 64,      lane, ko);
            bf16x8 xl1 = frag32(Xl, rh * 64 + 32, lane, ko);
            bf16x8 bq  = frag32(Wqh, ch * 32, lane, ko);
            bf16x8 bk  = frag32(Wkh, ch * 32, lane, ko);
            bf16x8 b1h = frag32(W1h, ch * 32, lane, ko);
            bf16x8 b1l = frag32(W1l, ch * 32, lane, ko);
            qa0 = MFMA32(xh0, bq, qa0);   qa1 = MFMA32(xh1, bq, qa1);
            ka0 = MFMA32(xh0, bk, ka0);   ka1 = MFMA32(xh1, bk, ka1);
            fa0 = MFMA32(xh0, b1h, fa0);  fa1 = MFMA32(xh1, b1h, fa1);
            fa0 = MFMA32(xl0, b1h, fa0);  fa1 = MFMA32(xl1, b1h, fa1);
            fa0 = MFMA32(xh0, b1l, fa0);  fa1 = MFMA32(xh1, b1l, fa1);
        }
    }
#undef LOAD_X
#undef LOAD_W
#undef STAGE_X
#undef STAGE_W

    // 32x32 C layout: col = lane&31, row = (g&3) + 8*(g>>2) + 4*(lane>>5)
    const int col = lane & 31;
    const int rb  = (lane >> 5) * 4;
#pragma unroll
    for (int g = 0; g < 16; ++g) {
        int r = (g & 3) + 8 * (g >> 2) + rb;
        long o0 = sOf + (row0 + rh * 64 + r) * 64 + ch * 32 + col;
        long o1 = o0 + 32 * 64;
        Qp[o0]  = qa0[g];  Qp[o1]  = qa1[g];
        Kp[o0]  = ka0[g];  Kp[o1]  = ka1[g];
        fcp[o0] = fa0[g];  fcp[o1] = fa1[g];
    }
}

// ---------------------------------------------------------------------------
// Sp[ks][b][j][d] = sum_{n in ks-slice} K[b,n,j] * x[b,n,d]
// K comes as 4 fp32 slabs (summed at staging). grid (16,8,8) = 1024 blocks.
// ---------------------------------------------------------------------------
__global__ __launch_bounds__(256) void s_kernel(
    const float* __restrict__ Kp, const float* __restrict__ x,
    float* __restrict__ Sp)
{
    __shared__ __align__(16) u16 Kt[64 * 72];
    __shared__ __align__(16) u16 Xt[64 * 72];

    const int tid = threadIdx.x, lane = tid & 63, wv = tid >> 6;
    const int dt = blockIdx.x, ks = blockIdx.y, b = blockIdx.z;
    const int n0 = ks * 256, d0 = dt * 64;

    const float* Kq = Kp + ((long)b * 2048 + n0) * 64;
    const float* xp = x  + ((long)b * 2048 + n0) * 1024 + d0;

    const f32x4 zero = {0.f, 0.f, 0.f, 0.f};
    f32x4 acc[4];
#pragma unroll
    for (int i = 0; i < 4; ++i) acc[i] = zero;

    float4 kf[4], xv[4];
#define SK_LOAD(NB)                                                           \
    {                                                                         \
        _Pragma("unroll")                                                     \
        for (int i = 0; i < 4; ++i) {                                         \
            long off = (long)((NB) + lane) * 64 + wv * 16 + i * 4;            \
            float4 a0 = *(const float4*)(Kq + off);                           \
            float4 a1 = *(const float4*)(Kq + 1048576 + off);                 \
            float4 a2 = *(const float4*)(Kq + 2097152 + off);                 \
            float4 a3 = *(const float4*)(Kq + 3145728 + off);                 \
            kf[i].x = (a0.x + a1.x) + (a2.x + a3.x);                          \
            kf[i].y = (a0.y + a1.y) + (a2.y + a3.y);                          \
            kf[i].z = (a0.z + a1.z) + (a2.z + a3.z);                          \
            kf[i].w = (a0.w + a1.w) + (a2.w + a3.w);                          \
            xv[i] = *(const float4*)(xp + (long)((NB) + lane) * 1024 + wv * 16 + i * 4); \
        }                                                                     \
    }

    SK_LOAD(0)
    for (int ch = 0; ch < 4; ++ch) {
        if (ch) __syncthreads();
#pragma unroll
        for (int i = 0; i < 4; ++i) {
            Kt[(wv * 16 + i * 4 + 0) * 72 + lane] = cvt1(kf[i].x);
            Kt[(wv * 16 + i * 4 + 1) * 72 + lane] = cvt1(kf[i].y);
            Kt[(wv * 16 + i * 4 + 2) * 72 + lane] = cvt1(kf[i].z);
            Kt[(wv * 16 + i * 4 + 3) * 72 + lane] = cvt1(kf[i].w);
            Xt[(wv * 16 + i * 4 + 0) * 72 + lane] = cvt1(xv[i].x);
            Xt[(wv * 16 + i * 4 + 1) * 72 + lane] = cvt1(xv[i].y);
            Xt[(wv * 16 + i * 4 + 2) * 72 + lane] = cvt1(xv[i].z);
            Xt[(wv * 16 + i * 4 + 3) * 72 + lane] = cvt1(xv[i].w);
        }
        __syncthreads();
        if (ch < 3) SK_LOAD((ch + 1) * 64)
#pragma unroll
        for (int kk = 0; kk < 64; kk += 32) {
            bf16x8 a = frag(Kt, wv * 16, lane, kk);
#pragma unroll
            for (int ct = 0; ct < 4; ++ct)
                acc[ct] = MFMA16(a, frag(Xt, ct * 16, lane, kk), acc[ct]);
        }
    }
#undef SK_LOAD

    float* C = Sp + ((long)ks * 8 + b) * 65536 + d0;
    const int rr = wv * 16 + (lane >> 4) * 4;
    const int cc = lane & 15;
#pragma unroll
    for (int ct = 0; ct < 4; ++ct)
#pragma unroll
        for (int g = 0; g < 4; ++g)
            C[(long)(rr + g) * 1024 + ct * 16 + cc] = acc[ct][g];
}

// ---------------------------------------------------------------------------
// 64x64 MFMA NT-GEMM: C[m,n] = sum_s Cin_s[m,n] + sum_k (sum A_s)*(sum B_s)
// AMODE: 0 fp32 row-major, 1 bf16 row-major.
// BMODE: 0 fp32 row-major, 1 bf16 row-major, 2 fp32 transposed [k][n].
// SPLIT: hi/lo 3-product accuracy. CSLAB: #fp32 C-init slabs (0 = none).
// ---------------------------------------------------------------------------
template <int AMODE, int BMODE, bool SPLIT, int ASLAB, int BSLAB, int CSLAB>
__global__ __launch_bounds__(256) void mm_nt(
    const void* __restrict__ Ap, int lda, long bsA, long slabA,
    const void* __restrict__ Bp, int ldb, long bsB, long slabB,
    float* __restrict__ Cp, int ldc, long bsC, long splitC,
    const float* __restrict__ Cin, long slabCin,
    int Kred, int nksplit)
{
    __shared__ __align__(16) u16 SMEM[(SPLIT ? 4 : 2) * 4608];
    u16* Ah = SMEM;
    u16* Bh = SMEM + 4608;
    u16* Al = SPLIT ? SMEM + 2 * 4608 : nullptr;
    u16* Bl = SPLIT ? SMEM + 3 * 4608 : nullptr;

    const int tid = threadIdx.x, lane = tid & 63, wv = tid >> 6;
    const int bm = blockIdx.x, bn = blockIdx.y;
    const int batch = blockIdx.z / nksplit;
    const int ks = blockIdx.z % nksplit;
    const int Kper = Kred / nksplit;
    const long kOff = (long)ks * Kper;

    const int r4 = tid >> 4, k4 = (tid & 15) * 4;   // mode-0 staging coords
    const int r8 = tid >> 3, k8 = (tid & 7) * 8;    // mode-1 staging coords

    const f32x4 zero = {0.f, 0.f, 0.f, 0.f};
    f32x4 acc[4];
#pragma unroll
    for (int i = 0; i < 4; ++i) acc[i] = zero;

    float4 fva[4], fvb[4];
    uint4  uva[2], uvb[2];
    float  tvb[16];

#define MM_LOADA(K0)                                                          \
    if constexpr (AMODE == 0) {                                               \
        const float* A = (const float*)Ap + (long)batch * bsA                 \
                       + (long)bm * 64 * lda + (K0);                          \
        _Pragma("unroll")                                                     \
        for (int i = 0; i < 4; ++i) {                                         \
            const float* p = A + (long)(r4 + i * 16) * lda + k4;              \
            float4 v = *(const float4*)p;                                     \
            _Pragma("unroll")                                                 \
            for (int s = 1; s < ASLAB; ++s) {                                 \
                float4 w = *(const float4*)(p + (long)s * slabA);             \
                v.x += w.x; v.y += w.y; v.z += w.z; v.w += w.w;               \
            }                                                                 \
            fva[i] = v;                                                       \
        }                                                                     \
    } else {                                                                  \
        const u16* A = (const u16*)Ap + (long)batch * bsA                     \
                     + (long)bm * 64 * lda + (K0);                            \
        _Pragma("unroll")                                                     \
        for (int i = 0; i < 2; ++i)                                           \
            uva[i] = *(const uint4*)(A + (long)(r8 + i * 32) * lda + k8);     \
    }
#define MM_LOADB(K0)                                                          \
    if constexpr (BMODE == 0) {                                               \
        const float* Bq = (const float*)Bp + (long)batch * bsB                \
                        + (long)bn * 64 * ldb + (K0);                         \
        _Pragma("unroll")                                                     \
        for (int i = 0; i < 4; ++i) {                                         \
            const float* p = Bq + (long)(r4 + i * 16) * ldb + k4;             \
            float4 v = *(const float4*)p;                                     \
            _Pragma("unroll")                                                 \
            for (int s = 1; s < BSLAB; ++s) {                                 \
                float4 w = *(const float4*)(p + (long)s * slabB);             \
                v.x += w.x; v.y += w.y; v.z += w.z; v.w += w.w;               \
            }                                                                 \
            fvb[i] = v;                                                       \
        }                                                                     \
    } else if constexpr (BMODE == 1) {                                        \
        const u16* Bq = (const u16*)Bp + (long)batch * bsB                    \
                      + (long)bn * 64 * ldb + (K0);                           \
        _Pragma("unroll")                                                     \
        for (int i = 0; i < 2; ++i)                                           \
            uvb[i] = *(const uint4*)(Bq + (long)(r8 + i * 32) * ldb + k8);    \
    } else {                                                                  \
        const float* Bq = (const float*)Bp + (long)batch * bsB                \
                        + (long)(K0) * ldb + (long)bn * 64;                   \
        _Pragma("unroll")                                                     \
        for (int i = 0; i < 16; ++i)                                          \
            tvb[i] = Bq[(long)((tid >> 6) + i * 4) * ldb + (tid & 63)];       \
    }

    MM_LOADA(kOff) MM_LOADB(kOff)
    for (int k0 = 0; k0 < Kper; k0 += 64) {
        if (k0) __syncthreads();
        // ---- store phase A ----
        if constexpr (AMODE == 0) {
#pragma unroll
            for (int i = 0; i < 4; ++i) {
                int r = r4 + i * 16;
                unsigned h01 = cvt2(fva[i].x, fva[i].y);
                unsigned h23 = cvt2(fva[i].z, fva[i].w);
                uint2 t; t.x = h01; t.y = h23;
                *(uint2*)&Ah[r * 72 + k4] = t;
                if constexpr (SPLIT) {
                    t.x = cvt2(fva[i].x - lo2f(h01), fva[i].y - hi2f(h01));
                    t.y = cvt2(fva[i].z - lo2f(h23), fva[i].w - hi2f(h23));
                    *(uint2*)&Al[r * 72 + k4] = t;
                }
            }
        } else {
#pragma unroll
            for (int i = 0; i < 2; ++i)
                *(uint4*)&Ah[(r8 + i * 32) * 72 + k8] = uva[i];
        }
        // ---- store phase B ----
        if constexpr (BMODE == 0) {
#pragma unroll
            for (int i = 0; i < 4; ++i) {
                int r = r4 + i * 16;
                unsigned h01 = cvt2(fvb[i].x, fvb[i].y);
                unsigned h23 = cvt2(fvb[i].z, fvb[i].w);
                uint2 t; t.x = h01; t.y = h23;
                *(uint2*)&Bh[r * 72 + k4] = t;
                if constexpr (SPLIT) {
                    t.x = cvt2(fvb[i].x - lo2f(h01), fvb[i].y - hi2f(h01));
                    t.y = cvt2(fvb[i].z - lo2f(h23), fvb[i].w - hi2f(h23));
                    *(uint2*)&Bl[r * 72 + k4] = t;
                }
            }
        } else if constexpr (BMODE == 1) {
#pragma unroll
            for (int i = 0; i < 2; ++i)
                *(uint4*)&Bh[(r8 + i * 32) * 72 + k8] = uvb[i];
        } else {
#pragma unroll
            for (int i = 0; i < 16; ++i)
                Bh[(tid & 63) * 72 + (tid >> 6) + i * 4] = cvt1(tvb[i]);
        }
        __syncthreads();
        if (k0 + 64 < Kper) { MM_LOADA(kOff + k0 + 64) MM_LOADB(kOff + k0 + 64) }
#pragma unroll
        for (int kk = 0; kk < 64; kk += 32) {
            bf16x8 ah = frag(Ah, wv * 16, lane, kk);
            bf16x8 al;
            if constexpr (SPLIT) al = frag(Al, wv * 16, lane, kk);
#pragma unroll
            for (int ct = 0; ct < 4; ++ct) {
                bf16x8 bh = frag(Bh, ct * 16, lane, kk);
                acc[ct] = MFMA16(ah, bh, acc[ct]);
                if constexpr (SPLIT) {
                    acc[ct] = MFMA16(al, bh, acc[ct]);
                    acc[ct] = MFMA16(ah, frag(Bl, ct * 16, lane, kk), acc[ct]);
                }
            }
        }
    }
#undef MM_LOADA
#undef MM_LOADB

    const long coff = (long)batch * bsC + (long)bm * 64 * ldc + (long)bn * 64;
    float* C = Cp + coff + (long)ks * splitC;
    const int rr = wv * 16 + (lane >> 4) * 4;
    const int cc = lane & 15;
#pragma unroll
    for (int ct = 0; ct < 4; ++ct)
#pragma unroll
        for (int g = 0; g < 4; ++g) {
            long idx = (long)(rr + g) * ldc + ct * 16 + cc;
            float v = acc[ct][g];
            if constexpr (CSLAB > 0) {
                const float* Ci = Cin + coff + idx;
#pragma unroll
                for (int s = 0; s < CSLAB; ++s) v += Ci[(long)s * slabCin];
            }
            C[idx] = v;
        }
}

// ---------------------------------------------------------------------------
extern "C" void kernel_launch(void* const* d_in, const int* in_sizes, int n_in,
                              void* d_out, int out_size, void* d_ws, size_t ws_size,
                              hipStream_t stream)
{
    const float* x  = (const float*)d_in[0];
    const float* Wq = (const float*)d_in[1];
    const float* Wk = (const float*)d_in[2];
    const float* Wv = (const float*)d_in[3];
    const float* W1 = (const float*)d_in[4];
    const float* W2 = (const float*)d_in[5];
    float* out = (float*)d_out;

    // Scratch (bytes): Qp/Kp/fcp 16M each (4 slabs), Sp 16M, Gp 2M, PBp 2M, fcb 4M
    const size_t QPB = 16777216, KPB = 16777216, FCPB = 16777216,
                 SPB = 16777216, GPB = 2097152, PBB = 2097152, FCB = 4194304;
    const size_t need = QPB + KPB + FCPB + SPB + GPB + PBB + FCB;  // 72 MB

    float *Qp, *Kp, *fcp, *Sp, *Gp, *PBp, *fcb;
    if (ws_size >= need) {
        char* w = (char*)d_ws;
        Qp  = (float*)w;  w += QPB;
        Kp  = (float*)w;  w += KPB;
        fcp = (float*)w;  w += FCPB;
        Sp  = (float*)w;  w += SPB;
        Gp  = (float*)w;  w += GPB;
        PBp = (float*)w;  w += PBB;
        fcb = (float*)w;
    } else {
        // Scratch in d_out (Qp+Kp+fcp+Sp = 64 MB exactly; all dead before the
        // final GEMM overwrites it); Gp/PBp/fcb (small) in ws.
        char* o = (char*)d_out;
        Qp  = (float*)o;  o += QPB;
        Kp  = (float*)o;  o += KPB;
        fcp = (float*)o;  o += FCPB;
        Sp  = (float*)o;
        char* w = (char*)d_ws;
        Gp  = (float*)w;  w += GPB;
        PBp = (float*)w;  w += PBB;
        fcb = (float*)w;
    }

    // 1) Qp/Kp/fcp partials over 4 k-quarters (512 blocks x 256 thr, 2 blk/CU)
    qkf_kernel<<<dim3(128, 4), 256, 0, stream>>>(x, Wq, Wk, W1, Qp, Kp, fcp);

    // 2) Sp[ks8][b][j][d] = (sum_4 Kp)_slice^T * x_slice  (1024 blocks)
    s_kernel<<<dim3(16, 8, 8), 256, 0, stream>>>(Kp, x, Sp);

    // 3) Gpart[ks8][k][d] = W1[k,:] * Wv[:,d]  (batch-independent, 128 blocks)
    mm_nt<0, 2, false, 1, 1, 0><<<dim3(1, 16, 8), 256, 0, stream>>>(
        W1, 1024, 0, 0,   Wv, 1024, 0, 0,
        Gp, 1024, 0, 65536L, nullptr, 0, 1024, 8);

    // 4) PBTpart[ks16][b][k][j] = (sum_8 Gpart)[k,:] * (sum_8 Sp)[b][j,:]^T  (128 blocks)
    mm_nt<0, 0, false, 8, 8, 0><<<dim3(1, 1, 128), 256, 0, stream>>>(
        Gp, 1024, 0, 65536L,   Sp, 1024, 65536L, 524288L,
        PBp, 64, 4096L, 32768L, nullptr, 0, 1024, 16);

    // 5) fcb = sum_4 fcp + (sum_4 Qp) * (sum_16 PBTpart)^T  (256 blocks)
    mm_nt<0, 0, false, 4, 16, 4><<<dim3(32, 1, 8), 256, 0, stream>>>(
        Qp, 64, 131072L, 1048576L,   PBp, 64, 4096L, 32768L,
        fcb, 64, 131072L, 0, fcp, 1048576L, 64, 1);

    // 6) out = fcb * W2^T (split-accurate both operands, 4096 blocks)
    mm_nt<0, 0, true, 1, 1, 0><<<dim3(256, 16, 1), 256, 0, stream>>>(
        fcb, 64, 0, 0,   W2, 64, 0, 0,
        out, 1024, 0, 0, nullptr, 0, 64, 1);
}

// Round 7
// 198.954 us; speedup vs baseline: 1.1966x; 1.1966x over previous
//
#include <hip/hip_runtime.h>

typedef __attribute__((ext_vector_type(8))) __bf16 bf16x8;
typedef __attribute__((ext_vector_type(4))) float f32x4;
typedef unsigned short u16;

#define MFMA16(a, b, c) __builtin_amdgcn_mfma_f32_16x16x32_bf16(a, b, c, 0, 0, 0)

// HW packed fp32->bf16 (RNE), 2 values per instruction. No builtin on gfx950.
__device__ __forceinline__ unsigned cvt2(float a, float b) {
    unsigned r;
    asm("v_cvt_pk_bf16_f32 %0, %1, %2" : "=v"(r) : "v"(a), "v"(b));
    return r;  // lo16 = bf16(a), hi16 = bf16(b)
}
__device__ __forceinline__ u16 cvt1(float a) { return (u16)cvt2(a, a); }
__device__ __forceinline__ float lo2f(unsigned p) { return __uint_as_float(p << 16); }
__device__ __forceinline__ float hi2f(unsigned p) { return __uint_as_float(p & 0xffff0000u); }

// LDS fragment: row = rtile + (lane&15), k = kofs + (lane>>4)*8; row stride 72 u16 (144B)
__device__ __forceinline__ bf16x8 frag(const u16* base, int rtile, int lane, int kofs) {
    return *(const bf16x8*)(base + (rtile + (lane & 15)) * 72 + kofs + (lane >> 4) * 8);
}

// ---------------------------------------------------------------------------
// Fused partial: for k-half ks (blockIdx.y), 64 rows (blockIdx.x):
//   Qp[ks] = x*Wq^T, Kp[ks] = x*Wk^T (fp32 partials)
//   fcp[ks] = x*W1^T (fp32, 3-product bf16 split)
// 512 threads / 8 waves; x stream 2-deep prefetch (ping-pong reg sets),
// weights 1-deep (L2-resident). cvt_pk staging. 2 blocks/CU.
// ---------------------------------------------------------------------------
__global__ __launch_bounds__(512, 4) void qkf_kernel(
    const float* __restrict__ x, const float* __restrict__ Wq,
    const float* __restrict__ Wk, const float* __restrict__ W1,
    float* __restrict__ Qp, float* __restrict__ Kp, float* __restrict__ fcp)
{
    __shared__ __align__(16) u16 SM[6 * 4608];
    u16* Xh  = SM;
    u16* Xl  = SM + 4608;
    u16* Wqh = SM + 2 * 4608;
    u16* Wkh = SM + 3 * 4608;
    u16* W1h = SM + 4 * 4608;
    u16* W1l = SM + 5 * 4608;

    const int tid  = threadIdx.x;
    const int lane = tid & 63;
    const int wv   = tid >> 6;           // 0..7
    const int rt   = (wv & 3) * 16;      // row tile
    const int ch2  = wv >> 2;            // ct half: ct in {2*ch2, 2*ch2+1}
    const long row0 = (long)blockIdx.x * 64;
    const int kb   = blockIdx.y * 512;          // k-half base
    const long sOf = (long)blockIdx.y * 1048576; // output slab offset

    const f32x4 zero = {0.f, 0.f, 0.f, 0.f};
    f32x4 qa[2], ka[2], fa[2];
#pragma unroll
    for (int i = 0; i < 2; ++i) { qa[i] = zero; ka[i] = zero; fa[i] = zero; }

    const int sr = tid >> 4;         // staging row 0..31
    const int sk = (tid & 15) * 4;   // staging k   0..60

    float4 xv0[2], xv1[2], qv[2], kv[2], w1v[2];

#define LOAD_X(S, K0)                                                         \
    { _Pragma("unroll")                                                       \
      for (int i = 0; i < 2; ++i)                                             \
          xv##S[i] = *(const float4*)(x + (row0 + sr + i * 32) * 1024 + (K0) + sk); }
#define LOAD_W(K0)                                                            \
    { _Pragma("unroll")                                                       \
      for (int i = 0; i < 2; ++i) {                                           \
          int r = sr + i * 32;                                                \
          qv[i]  = *(const float4*)(Wq + (long)r * 1024 + (K0) + sk);         \
          kv[i]  = *(const float4*)(Wk + (long)r * 1024 + (K0) + sk);         \
          w1v[i] = *(const float4*)(W1 + (long)r * 1024 + (K0) + sk);         \
      } }
#define CONV(S)                                                               \
    { _Pragma("unroll")                                                       \
      for (int i = 0; i < 2; ++i) {                                           \
          int r = sr + i * 32;                                                \
          unsigned xh01 = cvt2(xv##S[i].x, xv##S[i].y);                       \
          unsigned xh23 = cvt2(xv##S[i].z, xv##S[i].w);                       \
          unsigned xl01 = cvt2(xv##S[i].x - lo2f(xh01), xv##S[i].y - hi2f(xh01)); \
          unsigned xl23 = cvt2(xv##S[i].z - lo2f(xh23), xv##S[i].w - hi2f(xh23)); \
          uint2 t;                                                            \
          t.x = xh01; t.y = xh23; *(uint2*)&Xh[r * 72 + sk] = t;              \
          t.x = xl01; t.y = xl23; *(uint2*)&Xl[r * 72 + sk] = t;              \
          t.x = cvt2(qv[i].x, qv[i].y); t.y = cvt2(qv[i].z, qv[i].w);         \
          *(uint2*)&Wqh[r * 72 + sk] = t;                                     \
          t.x = cvt2(kv[i].x, kv[i].y); t.y = cvt2(kv[i].z, kv[i].w);         \
          *(uint2*)&Wkh[r * 72 + sk] = t;                                     \
          unsigned wh01 = cvt2(w1v[i].x, w1v[i].y);                           \
          unsigned wh23 = cvt2(w1v[i].z, w1v[i].w);                           \
          unsigned wl01 = cvt2(w1v[i].x - lo2f(wh01), w1v[i].y - hi2f(wh01)); \
          unsigned wl23 = cvt2(w1v[i].z - lo2f(wh23), w1v[i].w - hi2f(wh23)); \
          t.x = wh01; t.y = wh23; *(uint2*)&W1h[r * 72 + sk] = t;             \
          t.x = wl01; t.y = wl23; *(uint2*)&W1l[r * 72 + sk] = t;             \
      } }
#define MFMA_PHASE                                                            \
    { _Pragma("unroll")                                                       \
      for (int kk = 0; kk < 64; kk += 32) {                                   \
          bf16x8 ah = frag(Xh, rt, lane, kk);                                 \
          bf16x8 al = frag(Xl, rt, lane, kk);                                 \
          _Pragma("unroll")                                                   \
          for (int c = 0; c < 2; ++c) {                                       \
              int ct = ch2 * 2 + c;                                           \
              qa[c] = MFMA16(ah, frag(Wqh, ct * 16, lane, kk), qa[c]);        \
              ka[c] = MFMA16(ah, frag(Wkh, ct * 16, lane, kk), ka[c]);        \
              bf16x8 bh = frag(W1h, ct * 16, lane, kk);                       \
              fa[c] = MFMA16(ah, bh, fa[c]);                                  \
              fa[c] = MFMA16(al, bh, fa[c]);                                  \
              fa[c] = MFMA16(ah, frag(W1l, ct * 16, lane, kk), fa[c]);        \
          }                                                                   \
      } }

    // Prologue: x chunks 0,1 + weights chunk 0
    LOAD_X(0, kb) LOAD_X(1, kb + 64) LOAD_W(kb)

    for (int cp = 0; cp < 4; ++cp) {     // chunk pair (2cp, 2cp+1)
        const int kc = kb + cp * 128;
        // ---- chunk 2cp (x set 0) ----
        if (cp) __syncthreads();
        CONV(0)
        __syncthreads();
        if (cp < 3) LOAD_X(0, kc + 128)   // x chunk 2cp+2
        LOAD_W(kc + 64)                   // weights chunk 2cp+1
        MFMA_PHASE
        // ---- chunk 2cp+1 (x set 1) ----
        __syncthreads();
        CONV(1)
        __syncthreads();
        if (cp < 3) { LOAD_X(1, kc + 192) LOAD_W(kc + 128) }  // x 2cp+3, W 2cp+2
        MFMA_PHASE
    }
#undef LOAD_X
#undef LOAD_W
#undef CONV
#undef MFMA_PHASE

    // fp32 partial stores (C layout: col=lane&15, row=quad*4+g)
    const int rr = rt + (lane >> 4) * 4;
    const int cc = lane & 15;
#pragma unroll
    for (int c = 0; c < 2; ++c)
#pragma unroll
        for (int g = 0; g < 4; ++g) {
            long o = sOf + (row0 + rr + g) * 64 + (ch2 * 2 + c) * 16 + cc;
            Qp[o]  = qa[c][g];
            Kp[o]  = ka[c][g];
            fcp[o] = fa[c][g];
        }
}

// ---------------------------------------------------------------------------
// Kb[b,n,j] = bf16(Kp0 + Kp1)  — bit-identical to s_kernel's former
// (fp32 slab add -> cvt_pk RNE) path, done once instead of 16x per dt-tile.
// 512 blocks x 256 thr, 8 values/thread, fully coalesced.
// ---------------------------------------------------------------------------
__global__ __launch_bounds__(256) void ksum_kernel(
    const float* __restrict__ Kp, u16* __restrict__ Kb)
{
    const long g = ((long)blockIdx.x * 256 + threadIdx.x) * 8;
    float4 a0 = *(const float4*)(Kp + g);
    float4 a1 = *(const float4*)(Kp + g + 4);
    float4 b0 = *(const float4*)(Kp + 1048576 + g);
    float4 b1 = *(const float4*)(Kp + 1048576 + g + 4);
    uint4 r;
    r.x = cvt2(a0.x + b0.x, a0.y + b0.y);
    r.y = cvt2(a0.z + b0.z, a0.w + b0.w);
    r.z = cvt2(a1.x + b1.x, a1.y + b1.y);
    r.w = cvt2(a1.z + b1.z, a1.w + b1.w);
    *(uint4*)(Kb + g) = r;
}

// ---------------------------------------------------------------------------
// Sp[ks][b][j][d] = sum_{n in ks-slice} K[b,n,j] * x[b,n,d]
// K pre-summed bf16 (Kb). 2-deep prefetch on both streams.
// grid (16,8,8) = 1024 blocks.
// ---------------------------------------------------------------------------
__global__ __launch_bounds__(256) void s_kernel(
    const u16* __restrict__ Kb, const float* __restrict__ x,
    float* __restrict__ Sp)
{
    __shared__ __align__(16) u16 Kt[64 * 72];
    __shared__ __align__(16) u16 Xt[64 * 72];

    const int tid = threadIdx.x, lane = tid & 63, wv = tid >> 6;
    const int dt = blockIdx.x, ks = blockIdx.y, b = blockIdx.z;
    const int n0 = ks * 256, d0 = dt * 64;

    const u16*   Kq = Kb + ((long)b * 2048 + n0) * 64;
    const float* xp = x  + ((long)b * 2048 + n0) * 1024 + d0;

    const f32x4 zero = {0.f, 0.f, 0.f, 0.f};
    f32x4 acc[4];
#pragma unroll
    for (int i = 0; i < 4; ++i) acc[i] = zero;

    uint2  ku0[4], ku1[4];
    float4 xv0[4], xv1[4];

#define SK_LOAD(S, NB)                                                        \
    { _Pragma("unroll")                                                       \
      for (int i = 0; i < 4; ++i) {                                           \
          ku##S[i] = *(const uint2*)(Kq + (long)((NB) + lane) * 64 + wv * 16 + i * 4); \
          xv##S[i] = *(const float4*)(xp + (long)((NB) + lane) * 1024 + wv * 16 + i * 4); \
      } }
#define SK_STAGE(S)                                                           \
    { _Pragma("unroll")                                                       \
      for (int i = 0; i < 4; ++i) {                                           \
          int r = wv * 16 + i * 4;                                            \
          Kt[(r + 0) * 72 + lane] = (u16)(ku##S[i].x);                        \
          Kt[(r + 1) * 72 + lane] = (u16)(ku##S[i].x >> 16);                  \
          Kt[(r + 2) * 72 + lane] = (u16)(ku##S[i].y);                        \
          Kt[(r + 3) * 72 + lane] = (u16)(ku##S[i].y >> 16);                  \
          Xt[(r + 0) * 72 + lane] = cvt1(xv##S[i].x);                         \
          Xt[(r + 1) * 72 + lane] = cvt1(xv##S[i].y);                         \
          Xt[(r + 2) * 72 + lane] = cvt1(xv##S[i].z);                         \
          Xt[(r + 3) * 72 + lane] = cvt1(xv##S[i].w);                         \
      } }

    SK_LOAD(0, 0) SK_LOAD(1, 64)
#pragma unroll
    for (int ch = 0; ch < 4; ++ch) {
        if (ch) __syncthreads();
        if (ch & 1) { SK_STAGE(1) } else { SK_STAGE(0) }
        __syncthreads();
        if (ch < 2) {
            if (ch & 1) { SK_LOAD(1, (ch + 2) * 64) }
            else        { SK_LOAD(0, (ch + 2) * 64) }
        }
#pragma unroll
        for (int kk = 0; kk < 64; kk += 32) {
            bf16x8 a = frag(Kt, wv * 16, lane, kk);
#pragma unroll
            for (int ct = 0; ct < 4; ++ct)
                acc[ct] = MFMA16(a, frag(Xt, ct * 16, lane, kk), acc[ct]);
        }
    }
#undef SK_LOAD
#undef SK_STAGE

    float* C = Sp + ((long)ks * 8 + b) * 65536 + d0;
    const int rr = wv * 16 + (lane >> 4) * 4;
    const int cc = lane & 15;
#pragma unroll
    for (int ct = 0; ct < 4; ++ct)
#pragma unroll
        for (int g = 0; g < 4; ++g)
            C[(long)(rr + g) * 1024 + ct * 16 + cc] = acc[ct][g];
}

// ---------------------------------------------------------------------------
// 64x64 MFMA NT-GEMM: C[m,n] = sum_s Cin_s[m,n] + sum_k (sum A_s)*(sum B_s)
// AMODE: 0 fp32 row-major, 1 bf16 row-major.
// BMODE: 0 fp32 row-major, 1 bf16 row-major, 2 fp32 transposed [k][n].
// SPLIT: hi/lo 3-product accuracy. CSLAB: #fp32 C-init slabs (0 = none).
// ---------------------------------------------------------------------------
template <int AMODE, int BMODE, bool SPLIT, int ASLAB, int BSLAB, int CSLAB>
__global__ __launch_bounds__(256) void mm_nt(
    const void* __restrict__ Ap, int lda, long bsA, long slabA,
    const void* __restrict__ Bp, int ldb, long bsB, long slabB,
    float* __restrict__ Cp, int ldc, long bsC, long splitC,
    const float* __restrict__ Cin, long slabCin,
    int Kred, int nksplit)
{
    __shared__ __align__(16) u16 SMEM[(SPLIT ? 4 : 2) * 4608];
    u16* Ah = SMEM;
    u16* Bh = SMEM + 4608;
    u16* Al = SPLIT ? SMEM + 2 * 4608 : nullptr;
    u16* Bl = SPLIT ? SMEM + 3 * 4608 : nullptr;

    const int tid = threadIdx.x, lane = tid & 63, wv = tid >> 6;
    const int bm = blockIdx.x, bn = blockIdx.y;
    const int batch = blockIdx.z / nksplit;
    const int ks = blockIdx.z % nksplit;
    const int Kper = Kred / nksplit;
    const long kOff = (long)ks * Kper;

    const int r4 = tid >> 4, k4 = (tid & 15) * 4;   // mode-0 staging coords
    const int r8 = tid >> 3, k8 = (tid & 7) * 8;    // mode-1 staging coords

    const f32x4 zero = {0.f, 0.f, 0.f, 0.f};
    f32x4 acc[4];
#pragma unroll
    for (int i = 0; i < 4; ++i) acc[i] = zero;

    float4 fva[4], fvb[4];
    uint4  uva[2], uvb[2];
    float  tvb[16];

#define MM_LOADA(K0)                                                          \
    if constexpr (AMODE == 0) {                                               \
        const float* A = (const float*)Ap + (long)batch * bsA                 \
                       + (long)bm * 64 * lda + (K0);                          \
        _Pragma("unroll")                                                     \
        for (int i = 0; i < 4; ++i) {                                         \
            const float* p = A + (long)(r4 + i * 16) * lda + k4;              \
            float4 v = *(const float4*)p;                                     \
            _Pragma("unroll")                                                 \
            for (int s = 1; s < ASLAB; ++s) {                                 \
                float4 w = *(const float4*)(p + (long)s * slabA);             \
                v.x += w.x; v.y += w.y; v.z += w.z; v.w += w.w;               \
            }                                                                 \
            fva[i] = v;                                                       \
        }                                                                     \
    } else {                                                                  \
        const u16* A = (const u16*)Ap + (long)batch * bsA                     \
                     + (long)bm * 64 * lda + (K0);                            \
        _Pragma("unroll")                                                     \
        for (int i = 0; i < 2; ++i)                                           \
            uva[i] = *(const uint4*)(A + (long)(r8 + i * 32) * lda + k8);     \
    }
#define MM_LOADB(K0)                                                          \
    if constexpr (BMODE == 0) {                                               \
        const float* Bq = (const float*)Bp + (long)batch * bsB                \
                        + (long)bn * 64 * ldb + (K0);                         \
        _Pragma("unroll")                                                     \
        for (int i = 0; i < 4; ++i) {                                         \
            const float* p = Bq + (long)(r4 + i * 16) * ldb + k4;             \
            float4 v = *(const float4*)p;                                     \
            _Pragma("unroll")                                                 \
            for (int s = 1; s < BSLAB; ++s) {                                 \
                float4 w = *(const float4*)(p + (long)s * slabB);             \
                v.x += w.x; v.y += w.y; v.z += w.z; v.w += w.w;               \
            }                                                                 \
            fvb[i] = v;                                                       \
        }                                                                     \
    } else if constexpr (BMODE == 1) {                                        \
        const u16* Bq = (const u16*)Bp + (long)batch * bsB                    \
                      + (long)bn * 64 * ldb + (K0);                           \
        _Pragma("unroll")                                                     \
        for (int i = 0; i < 2; ++i)                                           \
            uvb[i] = *(const uint4*)(Bq + (long)(r8 + i * 32) * ldb + k8);    \
    } else {                                                                  \
        const float* Bq = (const float*)Bp + (long)batch * bsB                \
                        + (long)(K0) * ldb + (long)bn * 64;                   \
        _Pragma("unroll")                                                     \
        for (int i = 0; i < 16; ++i)                                          \
            tvb[i] = Bq[(long)((tid >> 6) + i * 4) * ldb + (tid & 63)];       \
    }

    MM_LOADA(kOff) MM_LOADB(kOff)
    for (int k0 = 0; k0 < Kper; k0 += 64) {
        if (k0) __syncthreads();
        // ---- store phase A ----
        if constexpr (AMODE == 0) {
#pragma unroll
            for (int i = 0; i < 4; ++i) {
                int r = r4 + i * 16;
                unsigned h01 = cvt2(fva[i].x, fva[i].y);
                unsigned h23 = cvt2(fva[i].z, fva[i].w);
                uint2 t; t.x = h01; t.y = h23;
                *(uint2*)&Ah[r * 72 + k4] = t;
                if constexpr (SPLIT) {
                    t.x = cvt2(fva[i].x - lo2f(h01), fva[i].y - hi2f(h01));
                    t.y = cvt2(fva[i].z - lo2f(h23), fva[i].w - hi2f(h23));
                    *(uint2*)&Al[r * 72 + k4] = t;
                }
            }
        } else {
#pragma unroll
            for (int i = 0; i < 2; ++i)
                *(uint4*)&Ah[(r8 + i * 32) * 72 + k8] = uva[i];
        }
        // ---- store phase B ----
        if constexpr (BMODE == 0) {
#pragma unroll
            for (int i = 0; i < 4; ++i) {
                int r = r4 + i * 16;
                unsigned h01 = cvt2(fvb[i].x, fvb[i].y);
                unsigned h23 = cvt2(fvb[i].z, fvb[i].w);
                uint2 t; t.x = h01; t.y = h23;
                *(uint2*)&Bh[r * 72 + k4] = t;
                if constexpr (SPLIT) {
                    t.x = cvt2(fvb[i].x - lo2f(h01), fvb[i].y - hi2f(h01));
                    t.y = cvt2(fvb[i].z - lo2f(h23), fvb[i].w - hi2f(h23));
                    *(uint2*)&Bl[r * 72 + k4] = t;
                }
            }
        } else if constexpr (BMODE == 1) {
#pragma unroll
            for (int i = 0; i < 2; ++i)
                *(uint4*)&Bh[(r8 + i * 32) * 72 + k8] = uvb[i];
        } else {
#pragma unroll
            for (int i = 0; i < 16; ++i)
                Bh[(tid & 63) * 72 + (tid >> 6) + i * 4] = cvt1(tvb[i]);
        }
        __syncthreads();
        if (k0 + 64 < Kper) { MM_LOADA(kOff + k0 + 64) MM_LOADB(kOff + k0 + 64) }
#pragma unroll
        for (int kk = 0; kk < 64; kk += 32) {
            bf16x8 ah = frag(Ah, wv * 16, lane, kk);
            bf16x8 al;
            if constexpr (SPLIT) al = frag(Al, wv * 16, lane, kk);
#pragma unroll
            for (int ct = 0; ct < 4; ++ct) {
                bf16x8 bh = frag(Bh, ct * 16, lane, kk);
                acc[ct] = MFMA16(ah, bh, acc[ct]);
                if constexpr (SPLIT) {
                    acc[ct] = MFMA16(al, bh, acc[ct]);
                    acc[ct] = MFMA16(ah, frag(Bl, ct * 16, lane, kk), acc[ct]);
                }
            }
        }
    }
#undef MM_LOADA
#undef MM_LOADB

    const long coff = (long)batch * bsC + (long)bm * 64 * ldc + (long)bn * 64;
    float* C = Cp + coff + (long)ks * splitC;
    const int rr = wv * 16 + (lane >> 4) * 4;
    const int cc = lane & 15;
#pragma unroll
    for (int ct = 0; ct < 4; ++ct)
#pragma unroll
        for (int g = 0; g < 4; ++g) {
            long idx = (long)(rr + g) * ldc + ct * 16 + cc;
            float v = acc[ct][g];
            if constexpr (CSLAB > 0) {
                const float* Ci = Cin + coff + idx;
#pragma unroll
                for (int s = 0; s < CSLAB; ++s) v += Ci[(long)s * slabCin];
            }
            C[idx] = v;
        }
}

// ---------------------------------------------------------------------------
extern "C" void kernel_launch(void* const* d_in, const int* in_sizes, int n_in,
                              void* d_out, int out_size, void* d_ws, size_t ws_size,
                              hipStream_t stream)
{
    const float* x  = (const float*)d_in[0];
    const float* Wq = (const float*)d_in[1];
    const float* Wk = (const float*)d_in[2];
    const float* Wv = (const float*)d_in[3];
    const float* W1 = (const float*)d_in[4];
    const float* W2 = (const float*)d_in[5];
    float* out = (float*)d_out;

    // Scratch (bytes): Qp 8M (2 slabs), Kp 8M, fcp 8M, Sp 16M, Gp 2M, PBp 2M,
    // fcb 4M, Kbf 2M
    const size_t QPB = 8388608, KPB = 8388608, FCPB = 8388608,
                 SPB = 16777216, GPB = 2097152, PBB = 2097152, FCB = 4194304,
                 KBFB = 2097152;
    const size_t need = QPB + KPB + FCPB + SPB + GPB + PBB + FCB + KBFB; // 54 MB

    float *Qp, *Kp, *fcp, *Sp, *Gp, *PBp, *fcb;
    u16* Kbf;
    if (ws_size >= need) {
        char* w = (char*)d_ws;
        Qp  = (float*)w;  w += QPB;
        Kp  = (float*)w;  w += KPB;
        fcp = (float*)w;  w += FCPB;
        Sp  = (float*)w;  w += SPB;
        Gp  = (float*)w;  w += GPB;
        PBp = (float*)w;  w += PBB;
        fcb = (float*)w;  w += FCB;
        Kbf = (u16*)w;
    } else {
        // Scratch in d_out (all dead before the final GEMM overwrites it);
        // fcb (read concurrently with out writes) in ws.
        char* o = (char*)d_out;
        Qp  = (float*)o;  o += QPB;
        Kp  = (float*)o;  o += KPB;
        fcp = (float*)o;  o += FCPB;
        Sp  = (float*)o;  o += SPB;
        Gp  = (float*)o;  o += GPB;
        PBp = (float*)o;  o += PBB;
        Kbf = (u16*)o;
        fcb = (float*)d_ws;
    }

    // 1) Qp/Kp/fcp partials over k-halves (512 blocks x 512 thr, 2 blk/CU)
    qkf_kernel<<<dim3(256, 2), 512, 0, stream>>>(x, Wq, Wk, W1, Qp, Kp, fcp);

    // 1b) Kbf = bf16(Kp0 + Kp1)  (512 blocks, bit-identical to old s staging)
    ksum_kernel<<<512, 256, 0, stream>>>(Kp, Kbf);

    // 2) Sp[ks8][b][j][d] = Kbf_slice^T * x_slice  (1024 blocks)
    s_kernel<<<dim3(16, 8, 8), 256, 0, stream>>>(Kbf, x, Sp);

    // 3) Gpart[ks8][k][d] = W1[k,:] * Wv[:,d]  (batch-independent, 128 blocks)
    mm_nt<0, 2, false, 1, 1, 0><<<dim3(1, 16, 8), 256, 0, stream>>>(
        W1, 1024, 0, 0,   Wv, 1024, 0, 0,
        Gp, 1024, 0, 65536L, nullptr, 0, 1024, 8);

    // 4) PBTpart[ks16][b][k][j] = (sum_8 Gpart)[k,:] * (sum_8 Sp)[b][j,:]^T  (128 blocks)
    mm_nt<0, 0, false, 8, 8, 0><<<dim3(1, 1, 128), 256, 0, stream>>>(
        Gp, 1024, 0, 65536L,   Sp, 1024, 65536L, 524288L,
        PBp, 64, 4096L, 32768L, nullptr, 0, 1024, 16);

    // 5) fcb = fcp0 + fcp1 + (Qp0+Qp1) * (sum_16 PBTpart)^T  (256 blocks)
    mm_nt<0, 0, false, 2, 16, 2><<<dim3(32, 1, 8), 256, 0, stream>>>(
        Qp, 64, 131072L, 1048576L,   PBp, 64, 4096L, 32768L,
        fcb, 64, 131072L, 0, fcp, 1048576L, 64, 1);

    // 6) out = fcb * W2^T (split-accurate both operands, 4096 blocks)
    mm_nt<0, 0, true, 1, 1, 0><<<dim3(256, 16, 1), 256, 0, stream>>>(
        fcb, 64, 0, 0,   W2, 64, 0, 0,
        out, 1024, 0, 0, nullptr, 0, 64, 1);
}

// Round 8
// 195.482 us; speedup vs baseline: 1.2179x; 1.0178x over previous
//
#include <hip/hip_runtime.h>

typedef __attribute__((ext_vector_type(8))) __bf16 bf16x8;
typedef __attribute__((ext_vector_type(4))) float f32x4;
typedef unsigned short u16;

#define MFMA16(a, b, c) __builtin_amdgcn_mfma_f32_16x16x32_bf16(a, b, c, 0, 0, 0)

// HW packed fp32->bf16 (RNE), 2 values per instruction. No builtin on gfx950.
__device__ __forceinline__ unsigned cvt2(float a, float b) {
    unsigned r;
    asm("v_cvt_pk_bf16_f32 %0, %1, %2" : "=v"(r) : "v"(a), "v"(b));
    return r;  // lo16 = bf16(a), hi16 = bf16(b)
}
__device__ __forceinline__ u16 cvt1(float a) { return (u16)cvt2(a, a); }
__device__ __forceinline__ float lo2f(unsigned p) { return __uint_as_float(p << 16); }
__device__ __forceinline__ float hi2f(unsigned p) { return __uint_as_float(p & 0xffff0000u); }

// LDS fragment: row = rtile + (lane&15), k = kofs + (lane>>4)*8; row stride 72 u16 (144B)
__device__ __forceinline__ bf16x8 frag(const u16* base, int rtile, int lane, int kofs) {
    return *(const bf16x8*)(base + (rtile + (lane & 15)) * 72 + kofs + (lane >> 4) * 8);
}

// ---------------------------------------------------------------------------
// Fused partial: for k-half ks (blockIdx.y), 64 rows (blockIdx.x):
//   Qp[ks] = x*Wq^T, Kp[ks] = x*Wk^T (fp32 partials)
//   fcp[ks] = x*W1^T (fp32, 3-product bf16 split)
// 256 threads / 4 waves; wave = 32x32 output (2 row-tiles x 2 ct-tiles,
// acc[2][2] register blocking): 12 LDS reads feed 20 MFMAs per kk
// (0.3 reads/MFMA vs 0.5 in the 1x2 design) -- LDS-read-BW relief.
// x stream 2-deep prefetch; cvt_pk staging. 2 blocks/CU.
// ---------------------------------------------------------------------------
__global__ __launch_bounds__(256, 2) void qkf_kernel(
    const float* __restrict__ x, const float* __restrict__ Wq,
    const float* __restrict__ Wk, const float* __restrict__ W1,
    float* __restrict__ Qp, float* __restrict__ Kp, float* __restrict__ fcp)
{
    __shared__ __align__(16) u16 SM[6 * 4608];
    u16* Xh  = SM;
    u16* Xl  = SM + 4608;
    u16* Wqh = SM + 2 * 4608;
    u16* Wkh = SM + 3 * 4608;
    u16* W1h = SM + 4 * 4608;
    u16* W1l = SM + 5 * 4608;

    const int tid  = threadIdx.x;
    const int lane = tid & 63;
    const int wv   = tid >> 6;           // 0..3
    const int rp   = wv >> 1;            // row pair: tiles rp*32, rp*32+16
    const int cp2  = wv & 1;             // ct pair: cts cp2*2, cp2*2+1
    const long row0 = (long)blockIdx.x * 64;
    const int kb   = blockIdx.y * 512;          // k-half base
    const long sOf = (long)blockIdx.y * 1048576; // output slab offset

    const f32x4 zero = {0.f, 0.f, 0.f, 0.f};
    f32x4 qa[2][2], ka[2][2], fa[2][2];
#pragma unroll
    for (int i = 0; i < 2; ++i)
#pragma unroll
        for (int j = 0; j < 2; ++j) { qa[i][j] = zero; ka[i][j] = zero; fa[i][j] = zero; }

    const int sr = tid >> 4;         // staging row 0..15
    const int sk = (tid & 15) * 4;   // staging k   0..60

    float4 xv0[4], xv1[4], qv[4], kv[4], w1v[4];

#define LOAD_X(S, K0)                                                         \
    { _Pragma("unroll")                                                       \
      for (int i = 0; i < 4; ++i)                                             \
          xv##S[i] = *(const float4*)(x + (row0 + sr + i * 16) * 1024 + (K0) + sk); }
#define LOAD_W(K0)                                                            \
    { _Pragma("unroll")                                                       \
      for (int i = 0; i < 4; ++i) {                                           \
          int r = sr + i * 16;                                                \
          qv[i]  = *(const float4*)(Wq + (long)r * 1024 + (K0) + sk);         \
          kv[i]  = *(const float4*)(Wk + (long)r * 1024 + (K0) + sk);         \
          w1v[i] = *(const float4*)(W1 + (long)r * 1024 + (K0) + sk);         \
      } }
#define CONV(S)                                                               \
    { _Pragma("unroll")                                                       \
      for (int i = 0; i < 4; ++i) {                                           \
          int r = sr + i * 16;                                                \
          unsigned xh01 = cvt2(xv##S[i].x, xv##S[i].y);                       \
          unsigned xh23 = cvt2(xv##S[i].z, xv##S[i].w);                       \
          unsigned xl01 = cvt2(xv##S[i].x - lo2f(xh01), xv##S[i].y - hi2f(xh01)); \
          unsigned xl23 = cvt2(xv##S[i].z - lo2f(xh23), xv##S[i].w - hi2f(xh23)); \
          uint2 t;                                                            \
          t.x = xh01; t.y = xh23; *(uint2*)&Xh[r * 72 + sk] = t;              \
          t.x = xl01; t.y = xl23; *(uint2*)&Xl[r * 72 + sk] = t;              \
          t.x = cvt2(qv[i].x, qv[i].y); t.y = cvt2(qv[i].z, qv[i].w);         \
          *(uint2*)&Wqh[r * 72 + sk] = t;                                     \
          t.x = cvt2(kv[i].x, kv[i].y); t.y = cvt2(kv[i].z, kv[i].w);         \
          *(uint2*)&Wkh[r * 72 + sk] = t;                                     \
          unsigned wh01 = cvt2(w1v[i].x, w1v[i].y);                           \
          unsigned wh23 = cvt2(w1v[i].z, w1v[i].w);                           \
          unsigned wl01 = cvt2(w1v[i].x - lo2f(wh01), w1v[i].y - hi2f(wh01)); \
          unsigned wl23 = cvt2(w1v[i].z - lo2f(wh23), w1v[i].w - hi2f(wh23)); \
          t.x = wh01; t.y = wh23; *(uint2*)&W1h[r * 72 + sk] = t;             \
          t.x = wl01; t.y = wl23; *(uint2*)&W1l[r * 72 + sk] = t;             \
      } }
#define MFMA_PHASE                                                            \
    { _Pragma("unroll")                                                       \
      for (int kk = 0; kk < 64; kk += 32) {                                   \
          bf16x8 ah0 = frag(Xh, rp * 32,      lane, kk);                      \
          bf16x8 ah1 = frag(Xh, rp * 32 + 16, lane, kk);                      \
          bf16x8 al0 = frag(Xl, rp * 32,      lane, kk);                      \
          bf16x8 al1 = frag(Xl, rp * 32 + 16, lane, kk);                      \
          _Pragma("unroll")                                                   \
          for (int c = 0; c < 2; ++c) {                                       \
              int ct = cp2 * 2 + c;                                           \
              bf16x8 bq = frag(Wqh, ct * 16, lane, kk);                       \
              qa[0][c] = MFMA16(ah0, bq, qa[0][c]);                           \
              qa[1][c] = MFMA16(ah1, bq, qa[1][c]);                           \
              bf16x8 bk = frag(Wkh, ct * 16, lane, kk);                       \
              ka[0][c] = MFMA16(ah0, bk, ka[0][c]);                           \
              ka[1][c] = MFMA16(ah1, bk, ka[1][c]);                           \
              bf16x8 bh = frag(W1h, ct * 16, lane, kk);                       \
              fa[0][c] = MFMA16(ah0, bh, fa[0][c]);                           \
              fa[0][c] = MFMA16(al0, bh, fa[0][c]);                           \
              fa[1][c] = MFMA16(ah1, bh, fa[1][c]);                           \
              fa[1][c] = MFMA16(al1, bh, fa[1][c]);                           \
              bf16x8 bl = frag(W1l, ct * 16, lane, kk);                       \
              fa[0][c] = MFMA16(ah0, bl, fa[0][c]);                           \
              fa[1][c] = MFMA16(ah1, bl, fa[1][c]);                           \
          }                                                                   \
      } }

    // Prologue: x chunks 0,1 + weights chunk 0
    LOAD_X(0, kb) LOAD_X(1, kb + 64) LOAD_W(kb)

    for (int cp = 0; cp < 4; ++cp) {     // chunk pair (2cp, 2cp+1)
        const int kc = kb + cp * 128;
        // ---- chunk 2cp (x set 0) ----
        if (cp) __syncthreads();
        CONV(0)
        __syncthreads();
        if (cp < 3) LOAD_X(0, kc + 128)   // x chunk 2cp+2
        LOAD_W(kc + 64)                   // weights chunk 2cp+1
        MFMA_PHASE
        // ---- chunk 2cp+1 (x set 1) ----
        __syncthreads();
        CONV(1)
        __syncthreads();
        if (cp < 3) { LOAD_X(1, kc + 192) LOAD_W(kc + 128) }  // x 2cp+3, W 2cp+2
        MFMA_PHASE
    }
#undef LOAD_X
#undef LOAD_W
#undef CONV
#undef MFMA_PHASE

    // fp32 partial stores (C layout: col=lane&15, row=quad*4+g)
    const int q4 = (lane >> 4) * 4;
    const int cc = lane & 15;
#pragma unroll
    for (int i = 0; i < 2; ++i)
#pragma unroll
        for (int c = 0; c < 2; ++c)
#pragma unroll
            for (int g = 0; g < 4; ++g) {
                long o = sOf + (row0 + rp * 32 + i * 16 + q4 + g) * 64
                       + (cp2 * 2 + c) * 16 + cc;
                Qp[o]  = qa[i][c][g];
                Kp[o]  = ka[i][c][g];
                fcp[o] = fa[i][c][g];
            }
}

// ---------------------------------------------------------------------------
// Kb[b,n,j] = bf16(Kp0 + Kp1)  — bit-identical to s_kernel's former
// (fp32 slab add -> cvt_pk RNE) path, done once instead of 16x per dt-tile.
// 512 blocks x 256 thr, 8 values/thread, fully coalesced.
// ---------------------------------------------------------------------------
__global__ __launch_bounds__(256) void ksum_kernel(
    const float* __restrict__ Kp, u16* __restrict__ Kb)
{
    const long g = ((long)blockIdx.x * 256 + threadIdx.x) * 8;
    float4 a0 = *(const float4*)(Kp + g);
    float4 a1 = *(const float4*)(Kp + g + 4);
    float4 b0 = *(const float4*)(Kp + 1048576 + g);
    float4 b1 = *(const float4*)(Kp + 1048576 + g + 4);
    uint4 r;
    r.x = cvt2(a0.x + b0.x, a0.y + b0.y);
    r.y = cvt2(a0.z + b0.z, a0.w + b0.w);
    r.z = cvt2(a1.x + b1.x, a1.y + b1.y);
    r.w = cvt2(a1.z + b1.z, a1.w + b1.w);
    *(uint4*)(Kb + g) = r;
}

// ---------------------------------------------------------------------------
// Sp[ks][b][j][d] = sum_{n in ks-slice} K[b,n,j] * x[b,n,d]
// K pre-summed bf16 (Kb). 2-deep prefetch on both streams.
// grid (16,8,8) = 1024 blocks.
// ---------------------------------------------------------------------------
__global__ __launch_bounds__(256) void s_kernel(
    const u16* __restrict__ Kb, const float* __restrict__ x,
    float* __restrict__ Sp)
{
    __shared__ __align__(16) u16 Kt[64 * 72];
    __shared__ __align__(16) u16 Xt[64 * 72];

    const int tid = threadIdx.x, lane = tid & 63, wv = tid >> 6;
    const int dt = blockIdx.x, ks = blockIdx.y, b = blockIdx.z;
    const int n0 = ks * 256, d0 = dt * 64;

    const u16*   Kq = Kb + ((long)b * 2048 + n0) * 64;
    const float* xp = x  + ((long)b * 2048 + n0) * 1024 + d0;

    const f32x4 zero = {0.f, 0.f, 0.f, 0.f};
    f32x4 acc[4];
#pragma unroll
    for (int i = 0; i < 4; ++i) acc[i] = zero;

    uint2  ku0[4], ku1[4];
    float4 xv0[4], xv1[4];

#define SK_LOAD(S, NB)                                                        \
    { _Pragma("unroll")                                                       \
      for (int i = 0; i < 4; ++i) {                                           \
          ku##S[i] = *(const uint2*)(Kq + (long)((NB) + lane) * 64 + wv * 16 + i * 4); \
          xv##S[i] = *(const float4*)(xp + (long)((NB) + lane) * 1024 + wv * 16 + i * 4); \
      } }
#define SK_STAGE(S)                                                           \
    { _Pragma("unroll")                                                       \
      for (int i = 0; i < 4; ++i) {                                           \
          int r = wv * 16 + i * 4;                                            \
          Kt[(r + 0) * 72 + lane] = (u16)(ku##S[i].x);                        \
          Kt[(r + 1) * 72 + lane] = (u16)(ku##S[i].x >> 16);                  \
          Kt[(r + 2) * 72 + lane] = (u16)(ku##S[i].y);                        \
          Kt[(r + 3) * 72 + lane] = (u16)(ku##S[i].y >> 16);                  \
          Xt[(r + 0) * 72 + lane] = cvt1(xv##S[i].x);                         \
          Xt[(r + 1) * 72 + lane] = cvt1(xv##S[i].y);                         \
          Xt[(r + 2) * 72 + lane] = cvt1(xv##S[i].z);                         \
          Xt[(r + 3) * 72 + lane] = cvt1(xv##S[i].w);                         \
      } }

    SK_LOAD(0, 0) SK_LOAD(1, 64)
#pragma unroll
    for (int ch = 0; ch < 4; ++ch) {
        if (ch) __syncthreads();
        if (ch & 1) { SK_STAGE(1) } else { SK_STAGE(0) }
        __syncthreads();
        if (ch < 2) {
            if (ch & 1) { SK_LOAD(1, (ch + 2) * 64) }
            else        { SK_LOAD(0, (ch + 2) * 64) }
        }
#pragma unroll
        for (int kk = 0; kk < 64; kk += 32) {
            bf16x8 a = frag(Kt, wv * 16, lane, kk);
#pragma unroll
            for (int ct = 0; ct < 4; ++ct)
                acc[ct] = MFMA16(a, frag(Xt, ct * 16, lane, kk), acc[ct]);
        }
    }
#undef SK_LOAD
#undef SK_STAGE

    float* C = Sp + ((long)ks * 8 + b) * 65536 + d0;
    const int rr = wv * 16 + (lane >> 4) * 4;
    const int cc = lane & 15;
#pragma unroll
    for (int ct = 0; ct < 4; ++ct)
#pragma unroll
        for (int g = 0; g < 4; ++g)
            C[(long)(rr + g) * 1024 + ct * 16 + cc] = acc[ct][g];
}

// ---------------------------------------------------------------------------
// 64x64 MFMA NT-GEMM: C[m,n] = sum_s Cin_s[m,n] + sum_k (sum A_s)*(sum B_s)
// AMODE: 0 fp32 row-major, 1 bf16 row-major.
// BMODE: 0 fp32 row-major, 1 bf16 row-major, 2 fp32 transposed [k][n].
// SPLIT: hi/lo 3-product accuracy. CSLAB: #fp32 C-init slabs (0 = none).
// ---------------------------------------------------------------------------
template <int AMODE, int BMODE, bool SPLIT, int ASLAB, int BSLAB, int CSLAB>
__global__ __launch_bounds__(256) void mm_nt(
    const void* __restrict__ Ap, int lda, long bsA, long slabA,
    const void* __restrict__ Bp, int ldb, long bsB, long slabB,
    float* __restrict__ Cp, int ldc, long bsC, long splitC,
    const float* __restrict__ Cin, long slabCin,
    int Kred, int nksplit)
{
    __shared__ __align__(16) u16 SMEM[(SPLIT ? 4 : 2) * 4608];
    u16* Ah = SMEM;
    u16* Bh = SMEM + 4608;
    u16* Al = SPLIT ? SMEM + 2 * 4608 : nullptr;
    u16* Bl = SPLIT ? SMEM + 3 * 4608 : nullptr;

    const int tid = threadIdx.x, lane = tid & 63, wv = tid >> 6;
    const int bm = blockIdx.x, bn = blockIdx.y;
    const int batch = blockIdx.z / nksplit;
    const int ks = blockIdx.z % nksplit;
    const int Kper = Kred / nksplit;
    const long kOff = (long)ks * Kper;

    const int r4 = tid >> 4, k4 = (tid & 15) * 4;   // mode-0 staging coords
    const int r8 = tid >> 3, k8 = (tid & 7) * 8;    // mode-1 staging coords

    const f32x4 zero = {0.f, 0.f, 0.f, 0.f};
    f32x4 acc[4];
#pragma unroll
    for (int i = 0; i < 4; ++i) acc[i] = zero;

    float4 fva[4], fvb[4];
    uint4  uva[2], uvb[2];
    float  tvb[16];

#define MM_LOADA(K0)                                                          \
    if constexpr (AMODE == 0) {                                               \
        const float* A = (const float*)Ap + (long)batch * bsA                 \
                       + (long)bm * 64 * lda + (K0);                          \
        _Pragma("unroll")                                                     \
        for (int i = 0; i < 4; ++i) {                                         \
            const float* p = A + (long)(r4 + i * 16) * lda + k4;              \
            float4 v = *(const float4*)p;                                     \
            _Pragma("unroll")                                                 \
            for (int s = 1; s < ASLAB; ++s) {                                 \
                float4 w = *(const float4*)(p + (long)s * slabA);             \
                v.x += w.x; v.y += w.y; v.z += w.z; v.w += w.w;               \
            }                                                                 \
            fva[i] = v;                                                       \
        }                                                                     \
    } else {                                                                  \
        const u16* A = (const u16*)Ap + (long)batch * bsA                     \
                     + (long)bm * 64 * lda + (K0);                            \
        _Pragma("unroll")                                                     \
        for (int i = 0; i < 2; ++i)                                           \
            uva[i] = *(const uint4*)(A + (long)(r8 + i * 32) * lda + k8);     \
    }
#define MM_LOADB(K0)                                                          \
    if constexpr (BMODE == 0) {                                               \
        const float* Bq = (const float*)Bp + (long)batch * bsB                \
                        + (long)bn * 64 * ldb + (K0);                         \
        _Pragma("unroll")                                                     \
        for (int i = 0; i < 4; ++i) {                                         \
            const float* p = Bq + (long)(r4 + i * 16) * ldb + k4;             \
            float4 v = *(const float4*)p;                                     \
            _Pragma("unroll")                                                 \
            for (int s = 1; s < BSLAB; ++s) {                                 \
                float4 w = *(const float4*)(p + (long)s * slabB);             \
                v.x += w.x; v.y += w.y; v.z += w.z; v.w += w.w;               \
            }                                                                 \
            fvb[i] = v;                                                       \
        }                                                                     \
    } else if constexpr (BMODE == 1) {                                        \
        const u16* Bq = (const u16*)Bp + (long)batch * bsB                    \
                      + (long)bn * 64 * ldb + (K0);                           \
        _Pragma("unroll")                                                     \
        for (int i = 0; i < 2; ++i)                                           \
            uvb[i] = *(const uint4*)(Bq + (long)(r8 + i * 32) * ldb + k8);    \
    } else {                                                                  \
        const float* Bq = (const float*)Bp + (long)batch * bsB                \
                        + (long)(K0) * ldb + (long)bn * 64;                   \
        _Pragma("unroll")                                                     \
        for (int i = 0; i < 16; ++i)                                          \
            tvb[i] = Bq[(long)((tid >> 6) + i * 4) * ldb + (tid & 63)];       \
    }

    MM_LOADA(kOff) MM_LOADB(kOff)
    for (int k0 = 0; k0 < Kper; k0 += 64) {
        if (k0) __syncthreads();
        // ---- store phase A ----
        if constexpr (AMODE == 0) {
#pragma unroll
            for (int i = 0; i < 4; ++i) {
                int r = r4 + i * 16;
                unsigned h01 = cvt2(fva[i].x, fva[i].y);
                unsigned h23 = cvt2(fva[i].z, fva[i].w);
                uint2 t; t.x = h01; t.y = h23;
                *(uint2*)&Ah[r * 72 + k4] = t;
                if constexpr (SPLIT) {
                    t.x = cvt2(fva[i].x - lo2f(h01), fva[i].y - hi2f(h01));
                    t.y = cvt2(fva[i].z - lo2f(h23), fva[i].w - hi2f(h23));
                    *(uint2*)&Al[r * 72 + k4] = t;
                }
            }
        } else {
#pragma unroll
            for (int i = 0; i < 2; ++i)
                *(uint4*)&Ah[(r8 + i * 32) * 72 + k8] = uva[i];
        }
        // ---- store phase B ----
        if constexpr (BMODE == 0) {
#pragma unroll
            for (int i = 0; i < 4; ++i) {
                int r = r4 + i * 16;
                unsigned h01 = cvt2(fvb[i].x, fvb[i].y);
                unsigned h23 = cvt2(fvb[i].z, fvb[i].w);
                uint2 t; t.x = h01; t.y = h23;
                *(uint2*)&Bh[r * 72 + k4] = t;
                if constexpr (SPLIT) {
                    t.x = cvt2(fvb[i].x - lo2f(h01), fvb[i].y - hi2f(h01));
                    t.y = cvt2(fvb[i].z - lo2f(h23), fvb[i].w - hi2f(h23));
                    *(uint2*)&Bl[r * 72 + k4] = t;
                }
            }
        } else if constexpr (BMODE == 1) {
#pragma unroll
            for (int i = 0; i < 2; ++i)
                *(uint4*)&Bh[(r8 + i * 32) * 72 + k8] = uvb[i];
        } else {
#pragma unroll
            for (int i = 0; i < 16; ++i)
                Bh[(tid & 63) * 72 + (tid >> 6) + i * 4] = cvt1(tvb[i]);
        }
        __syncthreads();
        if (k0 + 64 < Kper) { MM_LOADA(kOff + k0 + 64) MM_LOADB(kOff + k0 + 64) }
#pragma unroll
        for (int kk = 0; kk < 64; kk += 32) {
            bf16x8 ah = frag(Ah, wv * 16, lane, kk);
            bf16x8 al;
            if constexpr (SPLIT) al = frag(Al, wv * 16, lane, kk);
#pragma unroll
            for (int ct = 0; ct < 4; ++ct) {
                bf16x8 bh = frag(Bh, ct * 16, lane, kk);
                acc[ct] = MFMA16(ah, bh, acc[ct]);
                if constexpr (SPLIT) {
                    acc[ct] = MFMA16(al, bh, acc[ct]);
                    acc[ct] = MFMA16(ah, frag(Bl, ct * 16, lane, kk), acc[ct]);
                }
            }
        }
    }
#undef MM_LOADA
#undef MM_LOADB

    const long coff = (long)batch * bsC + (long)bm * 64 * ldc + (long)bn * 64;
    float* C = Cp + coff + (long)ks * splitC;
    const int rr = wv * 16 + (lane >> 4) * 4;
    const int cc = lane & 15;
#pragma unroll
    for (int ct = 0; ct < 4; ++ct)
#pragma unroll
        for (int g = 0; g < 4; ++g) {
            long idx = (long)(rr + g) * ldc + ct * 16 + cc;
            float v = acc[ct][g];
            if constexpr (CSLAB > 0) {
                const float* Ci = Cin + coff + idx;
#pragma unroll
                for (int s = 0; s < CSLAB; ++s) v += Ci[(long)s * slabCin];
            }
            C[idx] = v;
        }
}

// ---------------------------------------------------------------------------
extern "C" void kernel_launch(void* const* d_in, const int* in_sizes, int n_in,
                              void* d_out, int out_size, void* d_ws, size_t ws_size,
                              hipStream_t stream)
{
    const float* x  = (const float*)d_in[0];
    const float* Wq = (const float*)d_in[1];
    const float* Wk = (const float*)d_in[2];
    const float* Wv = (const float*)d_in[3];
    const float* W1 = (const float*)d_in[4];
    const float* W2 = (const float*)d_in[5];
    float* out = (float*)d_out;

    // Scratch (bytes): Qp 8M (2 slabs), Kp 8M, fcp 8M, Sp 16M, Gp 2M, PBp 2M,
    // fcb 4M, Kbf 2M
    const size_t QPB = 8388608, KPB = 8388608, FCPB = 8388608,
                 SPB = 16777216, GPB = 2097152, PBB = 2097152, FCB = 4194304,
                 KBFB = 2097152;
    const size_t need = QPB + KPB + FCPB + SPB + GPB + PBB + FCB + KBFB; // 54 MB

    float *Qp, *Kp, *fcp, *Sp, *Gp, *PBp, *fcb;
    u16* Kbf;
    if (ws_size >= need) {
        char* w = (char*)d_ws;
        Qp  = (float*)w;  w += QPB;
        Kp  = (float*)w;  w += KPB;
        fcp = (float*)w;  w += FCPB;
        Sp  = (float*)w;  w += SPB;
        Gp  = (float*)w;  w += GPB;
        PBp = (float*)w;  w += PBB;
        fcb = (float*)w;  w += FCB;
        Kbf = (u16*)w;
    } else {
        // Scratch in d_out (all dead before the final GEMM overwrites it);
        // fcb (read concurrently with out writes) in ws.
        char* o = (char*)d_out;
        Qp  = (float*)o;  o += QPB;
        Kp  = (float*)o;  o += KPB;
        fcp = (float*)o;  o += FCPB;
        Sp  = (float*)o;  o += SPB;
        Gp  = (float*)o;  o += GPB;
        PBp = (float*)o;  o += PBB;
        Kbf = (u16*)o;
        fcb = (float*)d_ws;
    }

    // 1) Qp/Kp/fcp partials over k-halves (512 blocks x 256 thr, 2 blk/CU)
    qkf_kernel<<<dim3(256, 2), 256, 0, stream>>>(x, Wq, Wk, W1, Qp, Kp, fcp);

    // 1b) Kbf = bf16(Kp0 + Kp1)  (512 blocks, bit-identical to old s staging)
    ksum_kernel<<<512, 256, 0, stream>>>(Kp, Kbf);

    // 2) Sp[ks8][b][j][d] = Kbf_slice^T * x_slice  (1024 blocks)
    s_kernel<<<dim3(16, 8, 8), 256, 0, stream>>>(Kbf, x, Sp);

    // 3) Gpart[ks8][k][d] = W1[k,:] * Wv[:,d]  (batch-independent, 128 blocks)
    mm_nt<0, 2, false, 1, 1, 0><<<dim3(1, 16, 8), 256, 0, stream>>>(
        W1, 1024, 0, 0,   Wv, 1024, 0, 0,
        Gp, 1024, 0, 65536L, nullptr, 0, 1024, 8);

    // 4) PBTpart[ks16][b][k][j] = (sum_8 Gpart)[k,:] * (sum_8 Sp)[b][j,:]^T  (128 blocks)
    mm_nt<0, 0, false, 8, 8, 0><<<dim3(1, 1, 128), 256, 0, stream>>>(
        Gp, 1024, 0, 65536L,   Sp, 1024, 65536L, 524288L,
        PBp, 64, 4096L, 32768L, nullptr, 0, 1024, 16);

    // 5) fcb = fcp0 + fcp1 + (Qp0+Qp1) * (sum_16 PBTpart)^T  (256 blocks)
    mm_nt<0, 0, false, 2, 16, 2><<<dim3(32, 1, 8), 256, 0, stream>>>(
        Qp, 64, 131072L, 1048576L,   PBp, 64, 4096L, 32768L,
        fcb, 64, 131072L, 0, fcp, 1048576L, 64, 1);

    // 6) out = fcb * W2^T (split-accurate both operands, 4096 blocks)
    mm_nt<0, 0, true, 1, 1, 0><<<dim3(256, 16, 1), 256, 0, stream>>>(
        fcb, 64, 0, 0,   W2, 64, 0, 0,
        out, 1024, 0, 0, nullptr, 0, 64, 1);
}